// Round 3
// baseline (16.700 us; speedup 1.0000x reference)
//
#include <hip/hip_runtime.h>

// KGW z-score watermark detector — split-row partial counts + finalize.
// token_ids: (B, S) integer (int64 or int32 buffer — auto-detected per block)
// lengths:   (B,)   integer (same dtype)
// out:       (B,)   float32 reward
//
// Kernel 1: grid B*NSPLIT, each block counts green tokens in its chunk of a
//           row -> d_ws partials (every slot written, no init needed).
// Kernel 2: one thread per row sums partials, computes z -> sigmoid -> out.

#define VOCAB 50257u
#define GREEN_SIZE 12564u
#define CW 4
#define HASH_KEY 15485863u      // < P, canonical
#define P31 2147483647u         // 2^31 - 1 (Mersenne prime)
#define NSPLIT 8
#define CHUNK_MAX 1024          // S/NSPLIT for S=8192
#define STAGE_MAX (CHUNK_MAX + CW)

// Lazy Mersenne mul-mod: inputs in [0, 2^31], output in [0, 2^31] with
// out === a*b (mod P). 2^31 === 1 (mod P) so folding top bits is exact.
__device__ __forceinline__ unsigned int mulmodP_lazy(unsigned int a, unsigned int b) {
    unsigned long long x = (unsigned long long)a * (unsigned long long)b; // <= 2^62
    unsigned int y = (unsigned int)(x & P31) + (unsigned int)(x >> 31);   // < 2^32
    return (y & P31) + (y >> 31);                                         // <= 2^31
}

__global__ __launch_bounds__(256) void kgw_partial(
        const void* __restrict__ tokens, const void* __restrict__ lengths,
        int* __restrict__ partial, int S) {
    __shared__ int s_tok[STAGE_MAX];
    __shared__ int s_red[4];
    __shared__ int s_any;

    const int bid = blockIdx.x;
    const int b   = bid >> 3;          // row
    const int p   = bid & (NSPLIT - 1);
    const int tid = threadIdx.x;
    const int CHUNK = S >> 3;          // 1024 for S=8192

    // dtype detect from first 2KB: int64 -> odd dwords all zero.
    if (tid == 0) s_any = 0;
    __syncthreads();
    if (((const unsigned int*)tokens)[2 * tid + 1] != 0u) atomicOr(&s_any, 1);
    __syncthreads();
    const int is64 = (s_any == 0);     // uniform

    const int Li = is64 ? (int)((const long long*)lengths)[b]
                        : ((const int*)lengths)[b];

    int t0 = p * CHUNK; if (t0 < CW) t0 = CW;
    int t1 = (p + 1) * CHUNK; if (t1 > Li) t1 = Li;

    int cnt = 0;
    if (t0 < t1) {                     // uniform per block
        const int base = t0 - CW;
        const int n = t1 - base;       // <= CHUNK + CW
        if (is64) {
            // low dword of little-endian int64 element (base+i) is dword 2*(..)
            const unsigned int* tp = (const unsigned int*)tokens
                                     + 2 * ((size_t)b * (size_t)S + (size_t)base);
            for (int i = tid; i < n; i += 256) s_tok[i] = (int)tp[2 * i] + 1;
        } else {
            const int* tp = (const int*)tokens + (size_t)b * (size_t)S + base;
            for (int i = tid; i < n; i += 256) s_tok[i] = tp[i] + 1;
        }
        __syncthreads();

        for (int t = t0 + tid; t < t1; t += 256) {
            const int j = t - base;    // >= CW
            unsigned int h = HASH_KEY;
            h = mulmodP_lazy(h, (unsigned int)s_tok[j - 1]);
            h = mulmodP_lazy(h, (unsigned int)s_tok[j - 2]);
            h = mulmodP_lazy(h, (unsigned int)s_tok[j - 3]);
            h = mulmodP_lazy(h, (unsigned int)s_tok[j - 4]);
            unsigned int g = mulmodP_lazy(h, (unsigned int)s_tok[j]);
            // canonicalize once: g in [0, 2^31] -> [0, P)
            g = (g & P31) + (g >> 31);
            if (g >= P31) g -= P31;
            cnt += ((g % VOCAB) < GREEN_SIZE) ? 1 : 0;
        }
    }

    // block reduce (all threads participate; idle threads hold 0)
    for (int off = 32; off > 0; off >>= 1) cnt += __shfl_down(cnt, off, 64);
    if ((tid & 63) == 0) s_red[tid >> 6] = cnt;
    __syncthreads();
    if (tid == 0) partial[bid] = s_red[0] + s_red[1] + s_red[2] + s_red[3];
}

__global__ __launch_bounds__(256) void kgw_final(
        const void* __restrict__ tokens, const void* __restrict__ lengths,
        const int* __restrict__ partial, float* __restrict__ out, int B) {
    __shared__ int s_any;
    if (threadIdx.x == 0) s_any = 0;
    __syncthreads();
    if (((const unsigned int*)tokens)[2 * threadIdx.x + 1] != 0u) atomicOr(&s_any, 1);
    __syncthreads();
    const int is64 = (s_any == 0);

    const int b = blockIdx.x * 256 + threadIdx.x;
    if (b >= B) return;

    const int Li = is64 ? (int)((const long long*)lengths)[b]
                        : ((const int*)lengths)[b];

    const int4* pp = (const int4*)(partial + b * NSPLIT);
    const int4 a = pp[0], c = pp[1];
    const int cnt = a.x + a.y + a.z + a.w + c.x + c.y + c.z + c.w;

    float r = 0.0f;
    if (Li >= CW + 1) {
        const float T = (float)(Li - CW);
        const float z = ((float)cnt - 0.25f * T) / sqrtf(0.1875f * T);
        r = 1.0f / (1.0f + expf(-(z - 2.0f) * 0.5f));
    }
    out[b] = r;
}

extern "C" void kernel_launch(void* const* d_in, const int* in_sizes, int n_in,
                              void* d_out, int out_size, void* d_ws, size_t ws_size,
                              hipStream_t stream) {
    const void* tokens  = d_in[0];
    const void* lengths = d_in[1];
    float* out   = (float*)d_out;
    int* partial = (int*)d_ws;

    const int B = out_size;               // 512
    const int S = in_sizes[0] / B;        // 8192

    kgw_partial<<<B * NSPLIT, 256, 0, stream>>>(tokens, lengths, partial, S);
    kgw_final<<<(B + 255) / 256, 256, 0, stream>>>(tokens, lengths, partial, out, B);
}

// Round 4
// 13.229 us; speedup vs baseline: 1.2624x; 1.2624x over previous
//
#include <hip/hip_runtime.h>

// KGW z-score watermark detector — single kernel, 1 block/row, 1024 threads.
// token_ids: (B, S) integer (int64 or int32 buffer — auto-detected per block)
// lengths:   (B,)   integer (same dtype)
// out:       (B,)   float32 reward
//
// green(t) iff ((HASH_KEY * prod_{i=0..4} (tok[t-i]+1)) mod P) mod VOCAB < GREEN_SIZE
// count over t in [CW, L) -> z = (count - g*T)/sqrt(g(1-g)T) -> sigmoid((z-2)/2).

#define VOCAB 50257u
#define GREEN_SIZE 12564u
#define CW 4
#define HASH_KEY 15485863u      // < P
#define P31 2147483647u         // 2^31 - 1 (Mersenne prime)
#define SMAX 8192
#define BLK 1024

// Lazy Mersenne mul-mod: inputs in [0, 2^31], output in [0, 2^31],
// out === a*b (mod P). Exact because 2^31 === 1 (mod P).
__device__ __forceinline__ unsigned int mulmodP_lazy(unsigned int a, unsigned int b) {
    unsigned long long x = (unsigned long long)a * (unsigned long long)b; // <= 2^62
    unsigned int y = (unsigned int)(x & P31) + (unsigned int)(x >> 31);   // < 2^32
    return (y & P31) + (y >> 31);                                         // <= 2^31
}

__global__ __launch_bounds__(BLK) void kgw_fused(
        const void* __restrict__ tokens, const void* __restrict__ lengths,
        float* __restrict__ out, int S) {
    __shared__ int s_tok[SMAX];
    __shared__ int s_red[BLK / 64];
    __shared__ int s_any;

    const int b   = blockIdx.x;
    const int tid = threadIdx.x;

    // --- dtype detect from first 2KB (first 256 threads).
    // int64 data: tokens < 50257 -> every odd dword is 0. int32: never all-zero.
    if (tid == 0) s_any = 0;
    __syncthreads();
    if (tid < 256 && ((const unsigned int*)tokens)[2 * tid + 1] != 0u)
        atomicOr(&s_any, 1);
    __syncthreads();
    const int is64 = (s_any == 0);   // uniform

    const int Li = is64 ? (int)((const long long*)lengths)[b]
                        : ((const int*)lengths)[b];

    if (Li < CW + 1) {               // uniform per block
        if (tid == 0) out[b] = 0.0f;
        return;
    }

    // --- stage tok[0..Li)+1 into LDS with 16B loads (row base is 16B aligned).
    if (is64) {
        const longlong2* tp2 = (const longlong2*)((const long long*)tokens + (size_t)b * (size_t)S);
        const int npair = Li >> 1;
        for (int i = tid; i < npair; i += BLK) {
            longlong2 v = tp2[i];
            s_tok[2 * i]     = (int)v.x + 1;
            s_tok[2 * i + 1] = (int)v.y + 1;
        }
        if ((Li & 1) && tid == 0)
            s_tok[Li - 1] = (int)((const long long*)tokens)[(size_t)b * (size_t)S + Li - 1] + 1;
    } else {
        const int* tp = (const int*)tokens + (size_t)b * (size_t)S;
        const int4* tp4 = (const int4*)tp;
        const int nq = Li >> 2;
        for (int i = tid; i < nq; i += BLK) {
            int4 v = tp4[i];
            s_tok[4 * i]     = v.x + 1;
            s_tok[4 * i + 1] = v.y + 1;
            s_tok[4 * i + 2] = v.z + 1;
            s_tok[4 * i + 3] = v.w + 1;
        }
        for (int t = 4 * nq + tid; t < Li; t += BLK) s_tok[t] = tp[t] + 1;
    }
    __syncthreads();

    // --- score tokens [CW, Li).
    int cnt = 0;
    for (int t = CW + tid; t < Li; t += BLK) {
        unsigned int h = HASH_KEY;
        h = mulmodP_lazy(h, (unsigned int)s_tok[t - 1]);
        h = mulmodP_lazy(h, (unsigned int)s_tok[t - 2]);
        h = mulmodP_lazy(h, (unsigned int)s_tok[t - 3]);
        h = mulmodP_lazy(h, (unsigned int)s_tok[t - 4]);
        unsigned int g = mulmodP_lazy(h, (unsigned int)s_tok[t]);
        g = (g & P31) + (g >> 31);            // canonicalize [0,2^31] -> [0,P)
        if (g >= P31) g -= P31;
        cnt += ((g % VOCAB) < GREEN_SIZE) ? 1 : 0;
    }

    // --- reduce: wave64 shuffle, then cross-wave via LDS (16 waves).
    for (int off = 32; off > 0; off >>= 1) cnt += __shfl_down(cnt, off, 64);
    if ((tid & 63) == 0) s_red[tid >> 6] = cnt;
    __syncthreads();

    if (tid == 0) {
        int c = 0;
        #pragma unroll
        for (int w = 0; w < BLK / 64; ++w) c += s_red[w];
        const float T = (float)(Li - CW);     // >= 1 here
        const float z = ((float)c - 0.25f * T) / sqrtf(0.1875f * T);
        out[b] = 1.0f / (1.0f + expf(-(z - 2.0f) * 0.5f));
    }
}

extern "C" void kernel_launch(void* const* d_in, const int* in_sizes, int n_in,
                              void* d_out, int out_size, void* d_ws, size_t ws_size,
                              hipStream_t stream) {
    const void* tokens  = d_in[0];
    const void* lengths = d_in[1];
    float* out = (float*)d_out;

    const int B = out_size;               // 512
    const int S = in_sizes[0] / B;        // 8192

    kgw_fused<<<B, BLK, 0, stream>>>(tokens, lengths, out, S);
}

// Round 5
// 12.445 us; speedup vs baseline: 1.3420x; 1.0630x over previous
//
#include <hip/hip_runtime.h>

// KGW z-score watermark detector — single kernel, single phase.
// token_ids: (B, S) integer (int64 or int32 buffer — wave-local auto-detect)
// lengths:   (B,)   integer (same dtype)
// out:       (B,)   float32 reward
//
// Each thread owns TPT=8 contiguous tokens of its row and loads its
// 12-token window (chunk + CW halo) directly into registers (16B loads,
// halo overlap absorbed by L1/L2). No staging LDS; one barrier total.
//
// green(t) iff ((HASH_KEY * prod_{i=0..4}(tok[t-i]+1)) mod P) mod VOCAB < GREEN
// count over t in [CW, L) -> z = (cnt - gT)/sqrt(g(1-g)T) -> sigmoid((z-2)/2).

#define VOCAB 50257u
#define GREEN_SIZE 12564u
#define CW 4
#define HASH_KEY 15485863u      // < P
#define P31 2147483647u         // 2^31 - 1 (Mersenne prime)
#define BLK 1024
#define TPT 8                   // tokens per thread; BLK*TPT == S == 8192

// Lazy Mersenne mul-mod: inputs in [0, 2^31], output in [0, 2^31],
// out === a*b (mod P). Exact because 2^31 === 1 (mod P).
__device__ __forceinline__ unsigned int mulmodP_lazy(unsigned int a, unsigned int b) {
    unsigned long long x = (unsigned long long)a * (unsigned long long)b; // <= 2^62
    unsigned int y = (unsigned int)(x & P31) + (unsigned int)(x >> 31);   // < 2^32
    return (y & P31) + (y >> 31);                                         // <= 2^31
}

__global__ __launch_bounds__(BLK) void kgw_fused(
        const void* __restrict__ tokens, const void* __restrict__ lengths,
        float* __restrict__ out, int S) {
    __shared__ int s_red[BLK / 64];

    const int b    = blockIdx.x;
    const int tid  = threadIdx.x;
    const int lane = tid & 63;

    // --- wave-local dtype detect, no barrier. int64 data: every odd dword
    // of the token buffer is 0 (values < 50257). int32: random tokens at
    // odd indices — 64 consecutive zeros ~ never.
    const unsigned int probe = ((const unsigned int*)tokens)[2 * lane + 1];
    const bool is64 = (__ballot(probe != 0u) == 0ull);   // wave-uniform

    const int Li = is64 ? (int)((const long long*)lengths)[b]
                        : ((const int*)lengths)[b];

    if (Li < CW + 1) {               // uniform per block
        if (tid == 0) out[b] = 0.0f;
        return;
    }

    const int t0 = CW + TPT * tid;   // first scored token of this thread
    int cnt = 0;
    if (t0 < Li) {
        unsigned int tok[TPT + CW];  // tokens (t0-CW .. t0+TPT-1), +1 applied
        if (is64) {
            const long long* row = (const long long*)tokens + (size_t)b * (size_t)S;
            #pragma unroll
            for (int k = 0; k < (TPT + CW) / 2; ++k) {        // 6 x 16B
                const int idx = TPT * tid + 2 * k;            // token t0-CW+2k
                const int vi  = min(idx, S - 2) >> 1;         // clamp: in-row
                const longlong2 v = ((const longlong2*)row)[vi];
                tok[2 * k]     = (unsigned int)v.x + 1u;
                tok[2 * k + 1] = (unsigned int)v.y + 1u;
            }
        } else {
            const int* row = (const int*)tokens + (size_t)b * (size_t)S;
            #pragma unroll
            for (int k = 0; k < (TPT + CW) / 4; ++k) {        // 3 x 16B
                const int idx = TPT * tid + 4 * k;
                const int vi  = min(idx, S - 4) >> 2;
                const int4 v = ((const int4*)row)[vi];
                tok[4 * k]     = (unsigned int)v.x + 1u;
                tok[4 * k + 1] = (unsigned int)v.y + 1u;
                tok[4 * k + 2] = (unsigned int)v.z + 1u;
                tok[4 * k + 3] = (unsigned int)v.w + 1u;
            }
        }
        // clamped slots correspond to token indices >= S, which are never
        // scored (t <= Li-1 <= S-1), so their garbage data is predicated off.

        #pragma unroll
        for (int j = 0; j < TPT; ++j) {                       // static indexing
            unsigned int h = HASH_KEY;
            h = mulmodP_lazy(h, tok[j]);
            h = mulmodP_lazy(h, tok[j + 1]);
            h = mulmodP_lazy(h, tok[j + 2]);
            h = mulmodP_lazy(h, tok[j + 3]);
            unsigned int g = mulmodP_lazy(h, tok[j + 4]);
            g = (g & P31) + (g >> 31);                        // -> [0, P)
            if (g >= P31) g -= P31;
            cnt += ((t0 + j < Li) && ((g % VOCAB) < GREEN_SIZE)) ? 1 : 0;
        }
    }

    // --- reduce: wave64 shuffle, then cross-wave via LDS (one barrier).
    for (int off = 32; off > 0; off >>= 1) cnt += __shfl_down(cnt, off, 64);
    if (lane == 0) s_red[tid >> 6] = cnt;
    __syncthreads();

    if (tid == 0) {
        int c = 0;
        #pragma unroll
        for (int w = 0; w < BLK / 64; ++w) c += s_red[w];
        const float T = (float)(Li - CW);                     // >= 1 here
        const float z = ((float)c - 0.25f * T) / sqrtf(0.1875f * T);
        out[b] = 1.0f / (1.0f + expf(-(z - 2.0f) * 0.5f));
    }
}

extern "C" void kernel_launch(void* const* d_in, const int* in_sizes, int n_in,
                              void* d_out, int out_size, void* d_ws, size_t ws_size,
                              hipStream_t stream) {
    const void* tokens  = d_in[0];
    const void* lengths = d_in[1];
    float* out = (float*)d_out;

    const int B = out_size;               // 512
    const int S = in_sizes[0] / B;        // 8192

    kgw_fused<<<B, BLK, 0, stream>>>(tokens, lengths, out, S);
}